// Round 1
// baseline (481.473 us; speedup 1.0000x reference)
//
#include <hip/hip_runtime.h>
#include <hip/hip_bf16.h>

#define BB 32
#define NN 1024
#define EE 16384
#define FIN 4
#define HH 4
#define CC 64
#define HC 256
#define NFC0 128
#define NEG 0.2f

// ---------------- CSR build ----------------
__global__ void k_zero(int* a, int n) {
    int i = blockIdx.x * blockDim.x + threadIdx.x;
    if (i < n) a[i] = 0;
}

__global__ void k_count(const int* __restrict__ ei, int* __restrict__ cnt) {
    int e = blockIdx.x * blockDim.x + threadIdx.x;
    if (e < EE) atomicAdd(&cnt[ei[EE + e]], 1);
}

__global__ void k_scan(int* __restrict__ cnt, int* __restrict__ off) {
    // single block, 1024 threads; exclusive scan; cnt becomes cursor copy
    __shared__ int s[NN];
    int t = threadIdx.x;
    int c = cnt[t];
    s[t] = c;
    __syncthreads();
    for (int d = 1; d < NN; d <<= 1) {
        int v = (t >= d) ? s[t - d] : 0;
        __syncthreads();
        s[t] += v;
        __syncthreads();
    }
    int excl = s[t] - c;
    off[t] = excl;
    cnt[t] = excl;            // reuse as scatter cursor
    if (t == NN - 1) off[NN] = s[NN - 1];
}

__global__ void k_scatter(const int* __restrict__ ei, int* __restrict__ cur,
                          int* __restrict__ csr) {
    int e = blockIdx.x * blockDim.x + threadIdx.x;
    if (e < EE) {
        int s = ei[e];
        int d = ei[EE + e];
        int p = atomicAdd(&cur[d], 1);
        csr[p] = s;
    }
}

// ---------------- layer 0 transform: h = x@W0, a_src, a_dst ----------------
__global__ __launch_bounds__(256) void k_transform0(
    const float* __restrict__ x, const float* __restrict__ W,
    const float* __restrict__ att_s, const float* __restrict__ att_d,
    float* __restrict__ h, float* __restrict__ as, float* __restrict__ ad) {
    int bn = blockIdx.x;
    int t = threadIdx.x;
    __shared__ float xs[FIN];
    if (t < FIN) xs[t] = x[bn * FIN + t];
    __syncthreads();
    float v = xs[0] * W[t] + xs[1] * W[HC + t] + xs[2] * W[2 * HC + t] +
              xs[3] * W[3 * HC + t];
    h[bn * HC + t] = v;
    int head = t >> 6, c = t & 63;
    float ps = v * att_s[head * CC + c];
    float pd = v * att_d[head * CC + c];
    for (int o = 32; o; o >>= 1) {
        ps += __shfl_xor(ps, o);
        pd += __shfl_xor(pd, o);
    }
    if (c == 0) {
        as[bn * HH + head] = ps;
        ad[bn * HH + head] = pd;
    }
}

// ---------------- GAT aggregate (softmax over in-edges, weighted sum) ------
__global__ __launch_bounds__(256) void k_aggregate(
    const float* __restrict__ h, const float* __restrict__ as,
    const float* __restrict__ ad, const int* __restrict__ off,
    const int* __restrict__ csr, const float* __restrict__ bias,
    const float* __restrict__ resid, float* __restrict__ out) {
    int bn = blockIdx.x;
    int b = bn >> 10;
    int n = bn & (NN - 1);
    int t = threadIdx.x;
    int head = t >> 6;
    int beg = off[n], end = off[n + 1];
    float adst = ad[bn * HH + head];
    __shared__ int srcs[256];

    // pass 1: per-head max logit
    float mx = -1e30f;
    for (int base = beg; base < end; base += 256) {
        int m = end - base; if (m > 256) m = 256;
        __syncthreads();
        if (t < m) srcs[t] = csr[base + t];
        __syncthreads();
        for (int j = 0; j < m; ++j) {
            int s = srcs[j];
            float l = as[((b << 10) + s) * HH + head] + adst;
            l = l > 0.f ? l : NEG * l;
            mx = fmaxf(mx, l);
        }
    }
    // pass 2: accumulate exp-weighted messages + denominator
    float acc = 0.f, den = 0.f;
    for (int base = beg; base < end; base += 256) {
        int m = end - base; if (m > 256) m = 256;
        __syncthreads();
        if (t < m) srcs[t] = csr[base + t];
        __syncthreads();
        for (int j = 0; j < m; ++j) {
            int s = srcs[j];
            float l = as[((b << 10) + s) * HH + head] + adst;
            l = l > 0.f ? l : NEG * l;
            float w = __expf(l - mx);
            den += w;
            acc += w * h[(size_t)(((b << 10) + s) << 8) + t];
        }
    }
    float o = acc / (den + 1e-16f) + bias[t];
    if (resid) o += resid[((size_t)bn << 8) + t];
    out[((size_t)bn << 8) + t] = o;
}

// ---------------- layer 1 transform: h = y@W1 (256x256) + a_src/a_dst -----
// tile: 32 nodes x 256 cols per block; thread = (tx:64 col-groups of 4, ty:4 node-groups of 8)
#define T1 32
#define YPAD 36
__global__ __launch_bounds__(256) void k_transform1(
    const float* __restrict__ y, const float* __restrict__ W,
    const float* __restrict__ att_s, const float* __restrict__ att_d,
    float* __restrict__ hout, float* __restrict__ as, float* __restrict__ ad) {
    __shared__ float ys[HC * YPAD];  // [k][node], padded
    int t = threadIdx.x;
    int bn0 = blockIdx.x * T1;
    for (int node = 0; node < T1; ++node)
        ys[t * YPAD + node] = y[(size_t)(bn0 + node) * HC + t];
    __syncthreads();

    int tx = t & 63, ty = t >> 6;
    int col0 = tx * 4, node0 = ty * 8;
    float acc[8][4];
#pragma unroll
    for (int i = 0; i < 8; ++i)
#pragma unroll
        for (int j = 0; j < 4; ++j) acc[i][j] = 0.f;

    for (int k = 0; k < HC; ++k) {
        float4 w = *(const float4*)&W[k * HC + col0];
        float4 ya = *(const float4*)&ys[k * YPAD + node0];
        float4 yb = *(const float4*)&ys[k * YPAD + node0 + 4];
        float yv[8] = {ya.x, ya.y, ya.z, ya.w, yb.x, yb.y, yb.z, yb.w};
#pragma unroll
        for (int i = 0; i < 8; ++i) {
            acc[i][0] += yv[i] * w.x;
            acc[i][1] += yv[i] * w.y;
            acc[i][2] += yv[i] * w.z;
            acc[i][3] += yv[i] * w.w;
        }
    }
    // store h
#pragma unroll
    for (int i = 0; i < 8; ++i) {
        float4 v = make_float4(acc[i][0], acc[i][1], acc[i][2], acc[i][3]);
        *(float4*)&hout[(size_t)(bn0 + node0 + i) * HC + col0] = v;
    }
    // fused a_src/a_dst: head = col0/64; reduce over 16 lanes (64 cols)
    int head = tx >> 4;
    int cbase = (tx & 15) * 4;
    float a0 = att_s[head * CC + cbase], a1 = att_s[head * CC + cbase + 1];
    float a2 = att_s[head * CC + cbase + 2], a3 = att_s[head * CC + cbase + 3];
    float d0 = att_d[head * CC + cbase], d1 = att_d[head * CC + cbase + 1];
    float d2 = att_d[head * CC + cbase + 2], d3 = att_d[head * CC + cbase + 3];
#pragma unroll
    for (int i = 0; i < 8; ++i) {
        float ps = acc[i][0] * a0 + acc[i][1] * a1 + acc[i][2] * a2 + acc[i][3] * a3;
        float pd = acc[i][0] * d0 + acc[i][1] * d1 + acc[i][2] * d2 + acc[i][3] * d3;
        for (int o = 8; o; o >>= 1) {
            ps += __shfl_xor(ps, o);
            pd += __shfl_xor(pd, o);
        }
        if ((tx & 15) == 0) {
            as[(bn0 + node0 + i) * HH + head] = ps;
            ad[(bn0 + node0 + i) * HH + head] = pd;
        }
    }
}

// ---------------- FC head: relu(y@fc0_w + fc0_b) @ fc1_w + fc1_b ----------
__global__ __launch_bounds__(128) void k_fc(
    const float* __restrict__ y, const float* __restrict__ w0,
    const float* __restrict__ b0f, const float* __restrict__ w1,
    const float* __restrict__ b1f, float* __restrict__ out) {
    int t = threadIdx.x;
    int bn0 = blockIdx.x * 16;
    __shared__ float ys[16 * HC];
    for (int idx = t; idx < 16 * HC; idx += 128)
        ys[idx] = y[(size_t)bn0 * HC + idx];
    __syncthreads();
    float acc[16];
#pragma unroll
    for (int i = 0; i < 16; ++i) acc[i] = 0.f;
    for (int k = 0; k < HC; k += 4) {
        float wa = w0[k * NFC0 + t];
        float wb = w0[(k + 1) * NFC0 + t];
        float wc = w0[(k + 2) * NFC0 + t];
        float wd = w0[(k + 3) * NFC0 + t];
#pragma unroll
        for (int i = 0; i < 16; ++i) {
            float4 yv = *(const float4*)&ys[i * HC + k];
            acc[i] += yv.x * wa + yv.y * wb + yv.z * wc + yv.w * wd;
        }
    }
    float bb = b0f[t], w1v = w1[t];
    __shared__ float red[2][16];
    float part[16];
#pragma unroll
    for (int i = 0; i < 16; ++i) {
        float z = acc[i] + bb;
        z = z > 0.f ? z : 0.f;
        part[i] = z * w1v;
    }
#pragma unroll
    for (int i = 0; i < 16; ++i) {
        float v = part[i];
        for (int o = 32; o; o >>= 1) v += __shfl_down(v, o);
        if ((t & 63) == 0) red[t >> 6][i] = v;
    }
    __syncthreads();
    if (t < 16) out[bn0 + t] = red[0][t] + red[1][t] + b1f[0];
}

// ---------------- launch ----------------
extern "C" void kernel_launch(void* const* d_in, const int* in_sizes, int n_in,
                              void* d_out, int out_size, void* d_ws, size_t ws_size,
                              hipStream_t stream) {
    const float* x = (const float*)d_in[0];
    // d_in[1] = e, ignored (edge_dim=None)
    const int* ei0 = (const int*)d_in[2];
    const int* ei1 = (const int*)d_in[3];
    const float* W0 = (const float*)d_in[4];
    const float* atts0 = (const float*)d_in[5];
    const float* attd0 = (const float*)d_in[6];
    const float* b0 = (const float*)d_in[7];
    const float* W1 = (const float*)d_in[8];
    const float* atts1 = (const float*)d_in[9];
    const float* attd1 = (const float*)d_in[10];
    const float* b1 = (const float*)d_in[11];
    const float* fc0w = (const float*)d_in[12];
    const float* fc0b = (const float*)d_in[13];
    const float* fc1w = (const float*)d_in[14];
    const float* fc1b = (const float*)d_in[15];
    float* out = (float*)d_out;

    // workspace layout
    size_t BNHC = (size_t)BB * NN * HC;   // 8388608 floats
    size_t BNH = (size_t)BB * NN * HH;    // 131072 floats
    float* fw = (float*)d_ws;
    float* h = fw;
    float* out0 = h + BNHC;
    float* y2 = out0 + BNHC;
    float* as0 = y2 + BNHC;
    float* ad0 = as0 + BNH;
    float* as1 = ad0 + BNH;
    float* ad1 = as1 + BNH;
    int* ip = (int*)(ad1 + BNH);
    int* off0 = ip; ip += NN + 1;
    int* off1 = ip; ip += NN + 1;
    int* cur0 = ip; ip += NN;
    int* cur1 = ip; ip += NN;
    int* csr0 = ip; ip += EE;
    int* csr1 = ip;

    // CSR build (edge indices shared across batch)
    k_zero<<<(2 * NN + 255) / 256, 256, 0, stream>>>(cur0, 2 * NN);
    k_count<<<EE / 256, 256, 0, stream>>>(ei0, cur0);
    k_count<<<EE / 256, 256, 0, stream>>>(ei1, cur1);
    k_scan<<<1, NN, 0, stream>>>(cur0, off0);
    k_scan<<<1, NN, 0, stream>>>(cur1, off1);
    k_scatter<<<EE / 256, 256, 0, stream>>>(ei0, cur0, csr0);
    k_scatter<<<EE / 256, 256, 0, stream>>>(ei1, cur1, csr1);

    // layer 0
    k_transform0<<<BB * NN, 256, 0, stream>>>(x, W0, atts0, attd0, h, as0, ad0);
    k_aggregate<<<BB * NN, 256, 0, stream>>>(h, as0, ad0, off0, csr0, b0,
                                             nullptr, out0);
    // layer 1 (+ residual)
    k_transform1<<<BB * NN / T1, 256, 0, stream>>>(out0, W1, atts1, attd1, h,
                                                   as1, ad1);
    k_aggregate<<<BB * NN, 256, 0, stream>>>(h, as1, ad1, off1, csr1, b1, out0,
                                             y2);
    // FC head
    k_fc<<<BB * NN / 16, 128, 0, stream>>>(y2, fc0w, fc0b, fc1w, fc1b, out);
}

// Round 2
// 351.594 us; speedup vs baseline: 1.3694x; 1.3694x over previous
//
#include <hip/hip_runtime.h>
#include <hip/hip_bf16.h>

#define BB 32
#define NN 1024
#define EE 16384
#define FIN 4
#define HH 4
#define CC 64
#define HC 256
#define NFC0 128
#define NEG 0.2f

// ---------------- float4 helpers ----------------
__device__ __forceinline__ float4 f4(float v) { return make_float4(v, v, v, v); }
__device__ __forceinline__ float4 f4max(float4 a, float4 b) {
    return make_float4(fmaxf(a.x, b.x), fmaxf(a.y, b.y), fmaxf(a.z, b.z), fmaxf(a.w, b.w));
}
__device__ __forceinline__ float4 f4add(float4 a, float4 b) {
    return make_float4(a.x + b.x, a.y + b.y, a.z + b.z, a.w + b.w);
}
__device__ __forceinline__ float4 f4sub(float4 a, float4 b) {
    return make_float4(a.x - b.x, a.y - b.y, a.z - b.z, a.w - b.w);
}
__device__ __forceinline__ float4 f4exp(float4 a) {
    return make_float4(__expf(a.x), __expf(a.y), __expf(a.z), __expf(a.w));
}
__device__ __forceinline__ float4 shflx4(float4 v, int o) {
    return make_float4(__shfl_xor(v.x, o), __shfl_xor(v.y, o),
                       __shfl_xor(v.z, o), __shfl_xor(v.w, o));
}
__device__ __forceinline__ float selh(float4 v, int h) {
    return h == 0 ? v.x : h == 1 ? v.y : h == 2 ? v.z : v.w;
}

// ---------------- CSR build (both edge lists fused) ----------------
__global__ void k_count2(const int* __restrict__ ei0, const int* __restrict__ ei1,
                         int* __restrict__ cnt) {
    int list = blockIdx.x >> 6;
    int e = ((blockIdx.x & 63) << 8) + threadIdx.x;
    const int* ei = list ? ei1 : ei0;
    atomicAdd(&cnt[(list << 10) + ei[EE + e]], 1);
}

__global__ void k_scan2(int* __restrict__ cnt, int* __restrict__ off) {
    __shared__ int s[NN];
    int list = blockIdx.x;
    int* c = cnt + (list << 10);
    int* o = off + list * (NN + 1);
    int t = threadIdx.x;
    int v0 = c[t];
    s[t] = v0;
    __syncthreads();
    for (int d = 1; d < NN; d <<= 1) {
        int v = (t >= d) ? s[t - d] : 0;
        __syncthreads();
        s[t] += v;
        __syncthreads();
    }
    int excl = s[t] - v0;
    o[t] = excl;
    c[t] = excl;   // becomes scatter cursor
    if (t == NN - 1) o[NN] = s[NN - 1];
}

__global__ void k_scatter2(const int* __restrict__ ei0, const int* __restrict__ ei1,
                           int* __restrict__ cur, int* __restrict__ csr) {
    int list = blockIdx.x >> 6;
    int e = ((blockIdx.x & 63) << 8) + threadIdx.x;
    const int* ei = list ? ei1 : ei0;
    int sv = ei[e];
    int d = ei[EE + e];
    int p = atomicAdd(&cur[(list << 10) + d], 1);
    csr[(list << 14) + p] = sv;
}

// ---------------- layer 0 transform: h = x@W0, a_src, a_dst ----------------
__global__ __launch_bounds__(256) void k_transform0(
    const float* __restrict__ x, const float* __restrict__ W,
    const float* __restrict__ att_s, const float* __restrict__ att_d,
    float* __restrict__ h, float* __restrict__ as, float* __restrict__ ad) {
    int bn = blockIdx.x;
    int t = threadIdx.x;
    __shared__ float xs[FIN];
    if (t < FIN) xs[t] = x[bn * FIN + t];
    __syncthreads();
    float v = xs[0] * W[t] + xs[1] * W[HC + t] + xs[2] * W[2 * HC + t] +
              xs[3] * W[3 * HC + t];
    h[bn * HC + t] = v;
    int head = t >> 6, c = t & 63;
    float ps = v * att_s[head * CC + c];
    float pd = v * att_d[head * CC + c];
    for (int o = 32; o; o >>= 1) {
        ps += __shfl_xor(ps, o);
        pd += __shfl_xor(pd, o);
    }
    if (c == 0) {
        as[bn * HH + head] = ps;
        ad[bn * HH + head] = pd;
    }
}

// -------- fused online-softmax GAT aggregate: 1 wave per (b,node) ---------
// block = 256 threads = 4 waves = 4 consecutive nodes (same b).
__global__ __launch_bounds__(256) void k_aggregate3(
    const float* __restrict__ h, const float* __restrict__ as,
    const float* __restrict__ ad, const int* __restrict__ off,
    const int* __restrict__ csr, const float* __restrict__ bias,
    const float* __restrict__ resid, float* __restrict__ out) {
    __shared__ int s_sh[4][64];
    __shared__ float e_sh[4][256];
    int t = threadIdx.x;
    int wid = t >> 6, tw = t & 63;
    int head = tw >> 4;                 // lane covers features [4tw,4tw+4) of this head
    int bn = (blockIdx.x << 2) + wid;
    int b = bn >> 10, n = bn & (NN - 1);
    int n0 = (blockIdx.x << 2) & (NN - 1);
    // uniform chunk count across the 4 waves (syncthreads legality)
    int o0 = off[n0], o1 = off[n0 + 1], o2 = off[n0 + 2], o3 = off[n0 + 3],
        o4 = off[n0 + 4];
    int maxdeg = max(max(o1 - o0, o2 - o1), max(o3 - o2, o4 - o3));
    int nchunk = (maxdeg + 63) >> 6;
    int beg = off[n], end = off[n + 1];
    const float* hb = h + ((size_t)b << 18) + (tw << 2);
    float4 adv = *(const float4*)&ad[bn << 2];
    float4 m4 = f4(-1e30f), den = f4(0.f), acc = f4(0.f);

    for (int c = 0; c < nchunk; ++c) {
        int base = beg + (c << 6);
        int m = end - base;
        if (m > 64) m = 64;
        __syncthreads();   // protect LDS reuse from previous chunk
        float4 lv = f4(-1e30f);
        if (tw < m) {
            int s = csr[base + tw];
            s_sh[wid][tw] = s;
            float4 av = *(const float4*)&as[((b << 10) + s) << 2];
            float4 z = f4add(av, adv);
            lv = make_float4(z.x > 0.f ? z.x : NEG * z.x,
                             z.y > 0.f ? z.y : NEG * z.y,
                             z.z > 0.f ? z.z : NEG * z.z,
                             z.w > 0.f ? z.w : NEG * z.w);
        }
        float4 cm = lv;
#pragma unroll
        for (int o = 32; o; o >>= 1) cm = f4max(cm, shflx4(cm, o));
        float4 nm = f4max(m4, cm);
        float4 r = f4exp(f4sub(m4, nm));   // first chunk: exp(-inf)=0
        m4 = nm;
        float4 ex = f4(0.f);
        if (tw < m) {
            ex = f4exp(f4sub(lv, m4));
            *(float4*)&e_sh[wid][tw << 2] = ex;
        }
        float4 cd = ex;
#pragma unroll
        for (int o = 32; o; o >>= 1) cd = f4add(cd, shflx4(cd, o));
        den = f4add(make_float4(den.x * r.x, den.y * r.y, den.z * r.z, den.w * r.w), cd);
        float rs = selh(r, head);
        acc.x *= rs; acc.y *= rs; acc.z *= rs; acc.w *= rs;
        __syncthreads();   // e_sh/s_sh visible to whole wave
        for (int j = 0; j < m; ++j) {
            int sj = s_sh[wid][j];
            float a = e_sh[wid][(j << 2) + head];
            float4 hv = *(const float4*)&hb[(size_t)sj << 8];
            acc.x += a * hv.x;
            acc.y += a * hv.y;
            acc.z += a * hv.z;
            acc.w += a * hv.w;
        }
    }
    float invd = 1.f / (selh(den, head) + 1e-16f);
    float4 bv = *(const float4*)&bias[tw << 2];
    float4 o;
    o.x = acc.x * invd + bv.x;
    o.y = acc.y * invd + bv.y;
    o.z = acc.z * invd + bv.z;
    o.w = acc.w * invd + bv.w;
    size_t ob = ((size_t)bn << 8) + (tw << 2);
    if (resid) {
        float4 rv = *(const float4*)&resid[ob];
        o.x += rv.x; o.y += rv.y; o.z += rv.z; o.w += rv.w;
    }
    *(float4*)&out[ob] = o;
}

// ---------------- layer 1 transform: h = y@W1 (256x256) + a_src/a_dst -----
#define T1 32
#define YPAD 36
__global__ __launch_bounds__(256) void k_transform1(
    const float* __restrict__ y, const float* __restrict__ W,
    const float* __restrict__ att_s, const float* __restrict__ att_d,
    float* __restrict__ hout, float* __restrict__ as, float* __restrict__ ad) {
    __shared__ float ys[HC * YPAD];  // [k][node], padded
    int t = threadIdx.x;
    int bn0 = blockIdx.x * T1;
    for (int node = 0; node < T1; ++node)
        ys[t * YPAD + node] = y[(size_t)(bn0 + node) * HC + t];
    __syncthreads();

    int tx = t & 63, ty = t >> 6;
    int col0 = tx * 4, node0 = ty * 8;
    float acc[8][4];
#pragma unroll
    for (int i = 0; i < 8; ++i)
#pragma unroll
        for (int j = 0; j < 4; ++j) acc[i][j] = 0.f;

    for (int k = 0; k < HC; ++k) {
        float4 w = *(const float4*)&W[k * HC + col0];
        float4 ya = *(const float4*)&ys[k * YPAD + node0];
        float4 yb = *(const float4*)&ys[k * YPAD + node0 + 4];
        float yv[8] = {ya.x, ya.y, ya.z, ya.w, yb.x, yb.y, yb.z, yb.w};
#pragma unroll
        for (int i = 0; i < 8; ++i) {
            acc[i][0] += yv[i] * w.x;
            acc[i][1] += yv[i] * w.y;
            acc[i][2] += yv[i] * w.z;
            acc[i][3] += yv[i] * w.w;
        }
    }
#pragma unroll
    for (int i = 0; i < 8; ++i) {
        float4 v = make_float4(acc[i][0], acc[i][1], acc[i][2], acc[i][3]);
        *(float4*)&hout[(size_t)(bn0 + node0 + i) * HC + col0] = v;
    }
    int head = tx >> 4;
    int cbase = (tx & 15) * 4;
    float a0 = att_s[head * CC + cbase], a1 = att_s[head * CC + cbase + 1];
    float a2 = att_s[head * CC + cbase + 2], a3 = att_s[head * CC + cbase + 3];
    float d0 = att_d[head * CC + cbase], d1 = att_d[head * CC + cbase + 1];
    float d2 = att_d[head * CC + cbase + 2], d3 = att_d[head * CC + cbase + 3];
#pragma unroll
    for (int i = 0; i < 8; ++i) {
        float ps = acc[i][0] * a0 + acc[i][1] * a1 + acc[i][2] * a2 + acc[i][3] * a3;
        float pd = acc[i][0] * d0 + acc[i][1] * d1 + acc[i][2] * d2 + acc[i][3] * d3;
        for (int o = 8; o; o >>= 1) {
            ps += __shfl_xor(ps, o);
            pd += __shfl_xor(pd, o);
        }
        if ((tx & 15) == 0) {
            as[(bn0 + node0 + i) * HH + head] = ps;
            ad[(bn0 + node0 + i) * HH + head] = pd;
        }
    }
}

// ---------------- FC head: relu(y@fc0_w + fc0_b) @ fc1_w + fc1_b ----------
__global__ __launch_bounds__(128) void k_fc(
    const float* __restrict__ y, const float* __restrict__ w0,
    const float* __restrict__ b0f, const float* __restrict__ w1,
    const float* __restrict__ b1f, float* __restrict__ out) {
    int t = threadIdx.x;
    int bn0 = blockIdx.x * 16;
    __shared__ float ys[16 * HC];
    for (int idx = t; idx < 16 * HC; idx += 128)
        ys[idx] = y[(size_t)bn0 * HC + idx];
    __syncthreads();
    float acc[16];
#pragma unroll
    for (int i = 0; i < 16; ++i) acc[i] = 0.f;
    for (int k = 0; k < HC; k += 4) {
        float wa = w0[k * NFC0 + t];
        float wb = w0[(k + 1) * NFC0 + t];
        float wc = w0[(k + 2) * NFC0 + t];
        float wd = w0[(k + 3) * NFC0 + t];
#pragma unroll
        for (int i = 0; i < 16; ++i) {
            float4 yv = *(const float4*)&ys[i * HC + k];
            acc[i] += yv.x * wa + yv.y * wb + yv.z * wc + yv.w * wd;
        }
    }
    float bb = b0f[t], w1v = w1[t];
    __shared__ float red[2][16];
    float part[16];
#pragma unroll
    for (int i = 0; i < 16; ++i) {
        float z = acc[i] + bb;
        z = z > 0.f ? z : 0.f;
        part[i] = z * w1v;
    }
#pragma unroll
    for (int i = 0; i < 16; ++i) {
        float v = part[i];
        for (int o = 32; o; o >>= 1) v += __shfl_down(v, o);
        if ((t & 63) == 0) red[t >> 6][i] = v;
    }
    __syncthreads();
    if (t < 16) out[bn0 + t] = red[0][t] + red[1][t] + b1f[0];
}

// ---------------- launch ----------------
extern "C" void kernel_launch(void* const* d_in, const int* in_sizes, int n_in,
                              void* d_out, int out_size, void* d_ws, size_t ws_size,
                              hipStream_t stream) {
    const float* x = (const float*)d_in[0];
    const int* ei0 = (const int*)d_in[2];
    const int* ei1 = (const int*)d_in[3];
    const float* W0 = (const float*)d_in[4];
    const float* atts0 = (const float*)d_in[5];
    const float* attd0 = (const float*)d_in[6];
    const float* b0 = (const float*)d_in[7];
    const float* W1 = (const float*)d_in[8];
    const float* atts1 = (const float*)d_in[9];
    const float* attd1 = (const float*)d_in[10];
    const float* b1 = (const float*)d_in[11];
    const float* fc0w = (const float*)d_in[12];
    const float* fc0b = (const float*)d_in[13];
    const float* fc1w = (const float*)d_in[14];
    const float* fc1b = (const float*)d_in[15];
    float* out = (float*)d_out;

    size_t BNHC = (size_t)BB * NN * HC;
    size_t BNH = (size_t)BB * NN * HH;
    float* fw = (float*)d_ws;
    float* h = fw;
    float* out0 = h + BNHC;
    float* y2 = out0 + BNHC;
    float* as0 = y2 + BNHC;
    float* ad0 = as0 + BNH;
    float* as1 = ad0 + BNH;
    float* ad1 = as1 + BNH;
    int* ip = (int*)(ad1 + BNH);
    int* off = ip; ip += 2 * (NN + 1);
    int* cnt = ip; ip += 2 * NN;      // becomes scatter cursor after scan
    int* csr = ip;                    // 2*EE

    hipMemsetAsync(cnt, 0, 2 * NN * sizeof(int), stream);
    k_count2<<<128, 256, 0, stream>>>(ei0, ei1, cnt);
    k_scan2<<<2, NN, 0, stream>>>(cnt, off);
    k_scatter2<<<128, 256, 0, stream>>>(ei0, ei1, cnt, csr);

    // layer 0
    k_transform0<<<BB * NN, 256, 0, stream>>>(x, W0, atts0, attd0, h, as0, ad0);
    k_aggregate3<<<BB * NN / 4, 256, 0, stream>>>(h, as0, ad0, off, csr, b0,
                                                  nullptr, out0);
    // layer 1 (+ residual)
    k_transform1<<<BB * NN / T1, 256, 0, stream>>>(out0, W1, atts1, attd1, h,
                                                   as1, ad1);
    k_aggregate3<<<BB * NN / 4, 256, 0, stream>>>(h, as1, ad1, off + (NN + 1),
                                                  csr + EE, b1, out0, y2);
    // FC head
    k_fc<<<BB * NN / 16, 128, 0, stream>>>(y2, fc0w, fc0b, fc1w, fc1b, out);
}

// Round 3
// 323.783 us; speedup vs baseline: 1.4870x; 1.0859x over previous
//
#include <hip/hip_runtime.h>
#include <hip/hip_bf16.h>

#define BB 32
#define NN 1024
#define EE 16384
#define FIN 4
#define HH 4
#define CC 64
#define HC 256
#define NFC0 128
#define NEG 0.2f

typedef unsigned short u16;
typedef u16 u16x8 __attribute__((ext_vector_type(8)));
typedef u16 u16x4 __attribute__((ext_vector_type(4)));
typedef short bf16x8 __attribute__((ext_vector_type(8)));
typedef float f32x4 __attribute__((ext_vector_type(4)));

__device__ __forceinline__ u16 f2bf(float f) {
    unsigned x = __float_as_uint(f);
    unsigned r = (x + 0x7fffu + ((x >> 16) & 1u)) >> 16;
    return (u16)r;
}
__device__ __forceinline__ float bf2f(u16 u) {
    return __uint_as_float(((unsigned)u) << 16);
}

// ---------------- float4 helpers ----------------
__device__ __forceinline__ float4 f4(float v) { return make_float4(v, v, v, v); }
__device__ __forceinline__ float4 f4max(float4 a, float4 b) {
    return make_float4(fmaxf(a.x, b.x), fmaxf(a.y, b.y), fmaxf(a.z, b.z), fmaxf(a.w, b.w));
}
__device__ __forceinline__ float4 f4add(float4 a, float4 b) {
    return make_float4(a.x + b.x, a.y + b.y, a.z + b.z, a.w + b.w);
}
__device__ __forceinline__ float4 f4sub(float4 a, float4 b) {
    return make_float4(a.x - b.x, a.y - b.y, a.z - b.z, a.w - b.w);
}
__device__ __forceinline__ float4 f4exp(float4 a) {
    return make_float4(__expf(a.x), __expf(a.y), __expf(a.z), __expf(a.w));
}
__device__ __forceinline__ float4 shflx4(float4 v, int o) {
    return make_float4(__shfl_xor(v.x, o), __shfl_xor(v.y, o),
                       __shfl_xor(v.z, o), __shfl_xor(v.w, o));
}
__device__ __forceinline__ float selh(float4 v, int h) {
    return h == 0 ? v.x : h == 1 ? v.y : h == 2 ? v.z : v.w;
}

// ---------------- CSR build (both edge lists fused) ----------------
__global__ void k_count2(const int* __restrict__ ei0, const int* __restrict__ ei1,
                         int* __restrict__ cnt) {
    int list = blockIdx.x >> 6;
    int e = ((blockIdx.x & 63) << 8) + threadIdx.x;
    const int* ei = list ? ei1 : ei0;
    atomicAdd(&cnt[(list << 10) + ei[EE + e]], 1);
}

__global__ void k_scan2(int* __restrict__ cnt, int* __restrict__ off) {
    __shared__ int s[NN];
    int list = blockIdx.x;
    int* c = cnt + (list << 10);
    int* o = off + list * (NN + 1);
    int t = threadIdx.x;
    int v0 = c[t];
    s[t] = v0;
    __syncthreads();
    for (int d = 1; d < NN; d <<= 1) {
        int v = (t >= d) ? s[t - d] : 0;
        __syncthreads();
        s[t] += v;
        __syncthreads();
    }
    int excl = s[t] - v0;
    o[t] = excl;
    c[t] = excl;   // becomes scatter cursor
    if (t == NN - 1) o[NN] = s[NN - 1];
}

__global__ void k_scatter2(const int* __restrict__ ei0, const int* __restrict__ ei1,
                           int* __restrict__ cur, int* __restrict__ csr) {
    int list = blockIdx.x >> 6;
    int e = ((blockIdx.x & 63) << 8) + threadIdx.x;
    const int* ei = list ? ei1 : ei0;
    int sv = ei[e];
    int d = ei[EE + e];
    int p = atomicAdd(&cur[(list << 10) + d], 1);
    csr[(list << 14) + p] = sv;
}

// ---------------- layer 0 transform: h = x@W0, a_src, a_dst ----------------
__global__ __launch_bounds__(256) void k_transform0(
    const float* __restrict__ x, const float* __restrict__ W,
    const float* __restrict__ att_s, const float* __restrict__ att_d,
    float* __restrict__ h, float* __restrict__ as, float* __restrict__ ad) {
    int bn = blockIdx.x;
    int t = threadIdx.x;
    __shared__ float xs[FIN];
    if (t < FIN) xs[t] = x[bn * FIN + t];
    __syncthreads();
    float v = xs[0] * W[t] + xs[1] * W[HC + t] + xs[2] * W[2 * HC + t] +
              xs[3] * W[3 * HC + t];
    h[bn * HC + t] = v;
    int head = t >> 6, c = t & 63;
    float ps = v * att_s[head * CC + c];
    float pd = v * att_d[head * CC + c];
    for (int o = 32; o; o >>= 1) {
        ps += __shfl_xor(ps, o);
        pd += __shfl_xor(pd, o);
    }
    if (c == 0) {
        as[bn * HH + head] = ps;
        ad[bn * HH + head] = pd;
    }
}

// -------- fused online-softmax GAT aggregate: 1 wave per (b,node) ---------
__global__ __launch_bounds__(256) void k_aggregate3(
    const float* __restrict__ h, const float* __restrict__ as,
    const float* __restrict__ ad, const int* __restrict__ off,
    const int* __restrict__ csr, const float* __restrict__ bias,
    const float* __restrict__ resid, float* __restrict__ out,
    u16* __restrict__ yhi, u16* __restrict__ ylo) {
    __shared__ int s_sh[4][64];
    __shared__ float e_sh[4][256];
    int t = threadIdx.x;
    int wid = t >> 6, tw = t & 63;
    int head = tw >> 4;
    int bn = (blockIdx.x << 2) + wid;
    int b = bn >> 10, n = bn & (NN - 1);
    int n0 = (blockIdx.x << 2) & (NN - 1);
    int o0 = off[n0], o1 = off[n0 + 1], o2 = off[n0 + 2], o3 = off[n0 + 3],
        o4 = off[n0 + 4];
    int maxdeg = max(max(o1 - o0, o2 - o1), max(o3 - o2, o4 - o3));
    int nchunk = (maxdeg + 63) >> 6;
    int beg = off[n], end = off[n + 1];
    const float* hb = h + ((size_t)b << 18) + (tw << 2);
    float4 adv = *(const float4*)&ad[bn << 2];
    float4 m4 = f4(-1e30f), den = f4(0.f), acc = f4(0.f);

    for (int c = 0; c < nchunk; ++c) {
        int base = beg + (c << 6);
        int m = end - base;
        if (m > 64) m = 64;
        __syncthreads();
        float4 lv = f4(-1e30f);
        if (tw < m) {
            int s = csr[base + tw];
            s_sh[wid][tw] = s;
            float4 av = *(const float4*)&as[((b << 10) + s) << 2];
            float4 z = f4add(av, adv);
            lv = make_float4(z.x > 0.f ? z.x : NEG * z.x,
                             z.y > 0.f ? z.y : NEG * z.y,
                             z.z > 0.f ? z.z : NEG * z.z,
                             z.w > 0.f ? z.w : NEG * z.w);
        }
        float4 cm = lv;
#pragma unroll
        for (int o = 32; o; o >>= 1) cm = f4max(cm, shflx4(cm, o));
        float4 nm = f4max(m4, cm);
        float4 r = f4exp(f4sub(m4, nm));
        m4 = nm;
        float4 ex = f4(0.f);
        if (tw < m) {
            ex = f4exp(f4sub(lv, m4));
            *(float4*)&e_sh[wid][tw << 2] = ex;
        }
        float4 cd = ex;
#pragma unroll
        for (int o = 32; o; o >>= 1) cd = f4add(cd, shflx4(cd, o));
        den = f4add(make_float4(den.x * r.x, den.y * r.y, den.z * r.z, den.w * r.w), cd);
        float rs = selh(r, head);
        acc.x *= rs; acc.y *= rs; acc.z *= rs; acc.w *= rs;
        __syncthreads();
        for (int j = 0; j < m; ++j) {
            int sj = s_sh[wid][j];
            float a = e_sh[wid][(j << 2) + head];
            float4 hv = *(const float4*)&hb[(size_t)sj << 8];
            acc.x += a * hv.x;
            acc.y += a * hv.y;
            acc.z += a * hv.z;
            acc.w += a * hv.w;
        }
    }
    float invd = 1.f / (selh(den, head) + 1e-16f);
    float4 bv = *(const float4*)&bias[tw << 2];
    float4 o;
    o.x = acc.x * invd + bv.x;
    o.y = acc.y * invd + bv.y;
    o.z = acc.z * invd + bv.z;
    o.w = acc.w * invd + bv.w;
    size_t ob = ((size_t)bn << 8) + (tw << 2);
    if (resid) {
        float4 rv = *(const float4*)&resid[ob];
        o.x += rv.x; o.y += rv.y; o.z += rv.z; o.w += rv.w;
    }
    *(float4*)&out[ob] = o;
    if (yhi) {
        u16x4 hv, lv;
        hv[0] = f2bf(o.x); lv[0] = f2bf(o.x - bf2f(hv[0]));
        hv[1] = f2bf(o.y); lv[1] = f2bf(o.y - bf2f(hv[1]));
        hv[2] = f2bf(o.z); lv[2] = f2bf(o.z - bf2f(hv[2]));
        hv[3] = f2bf(o.w); lv[3] = f2bf(o.w - bf2f(hv[3]));
        *(u16x4*)&yhi[ob] = hv;
        *(u16x4*)&ylo[ob] = lv;
    }
}

// ---------------- W1 -> W1^T bf16 hi/lo ----------------
__global__ __launch_bounds__(256) void k_prepW(const float* __restrict__ W,
                                               u16* __restrict__ wthi,
                                               u16* __restrict__ wtlo) {
    int c = blockIdx.x, k = threadIdx.x;
    float v = W[k * HC + c];
    u16 hi = f2bf(v);
    u16 lo = f2bf(v - bf2f(hi));
    wthi[c * HC + k] = hi;
    wtlo[c * HC + k] = lo;
}

// ------- layer 1 transform via split-bf16 MFMA: h = y@W1, a_src/a_dst -----
// block tile 128x128, 4 waves (2x2), wave tile 64x64 of 16x16x32 frags.
#define LKP 40
__global__ __launch_bounds__(256) void k_transform1_mfma(
    const u16* __restrict__ yhi, const u16* __restrict__ ylo,
    const u16* __restrict__ wthi, const u16* __restrict__ wtlo,
    const float* __restrict__ att_s, const float* __restrict__ att_d,
    float* __restrict__ hout, float* __restrict__ as, float* __restrict__ ad) {
    __shared__ u16 Ah[128][LKP];
    __shared__ u16 Al[128][LKP];
    __shared__ u16 Bh[128][LKP];
    __shared__ u16 Bl[128][LKP];
    int t = threadIdx.x;
    int tm = blockIdx.x >> 1, tn = blockIdx.x & 1;
    int l = t & 63, wid = t >> 6;
    int wr = wid >> 1, wc = wid & 1;
    int srow = t >> 2, sseg = (t & 3) << 3;

    const u16* Ab0 = yhi + ((size_t)(tm * 128 + srow) << 8) + sseg;
    const u16* Ab1 = Ab0 + (64 << 8);
    const u16* Alo0 = ylo + ((size_t)(tm * 128 + srow) << 8) + sseg;
    const u16* Alo1 = Alo0 + (64 << 8);
    const u16* Bb0 = wthi + ((tn * 128 + srow) << 8) + sseg;
    const u16* Bb1 = Bb0 + (64 << 8);
    const u16* Blo0 = wtlo + ((tn * 128 + srow) << 8) + sseg;
    const u16* Blo1 = Blo0 + (64 << 8);

    f32x4 acc[4][4];
#pragma unroll
    for (int i = 0; i < 4; ++i)
#pragma unroll
        for (int j = 0; j < 4; ++j) acc[i][j] = (f32x4){0.f, 0.f, 0.f, 0.f};

    int kb = (l >> 4) << 3;
    int rA = wr * 64 + (l & 15);
    int rB = wc * 64 + (l & 15);

    for (int kt = 0; kt < 8; ++kt) {
        int k0 = kt << 5;
        u16x8 va0 = *(const u16x8*)(Ab0 + k0);
        u16x8 va1 = *(const u16x8*)(Ab1 + k0);
        u16x8 vla0 = *(const u16x8*)(Alo0 + k0);
        u16x8 vla1 = *(const u16x8*)(Alo1 + k0);
        u16x8 vb0 = *(const u16x8*)(Bb0 + k0);
        u16x8 vb1 = *(const u16x8*)(Bb1 + k0);
        u16x8 vlb0 = *(const u16x8*)(Blo0 + k0);
        u16x8 vlb1 = *(const u16x8*)(Blo1 + k0);
        __syncthreads();
        *(u16x8*)&Ah[srow][sseg] = va0;
        *(u16x8*)&Ah[srow + 64][sseg] = va1;
        *(u16x8*)&Al[srow][sseg] = vla0;
        *(u16x8*)&Al[srow + 64][sseg] = vla1;
        *(u16x8*)&Bh[srow][sseg] = vb0;
        *(u16x8*)&Bh[srow + 64][sseg] = vb1;
        *(u16x8*)&Bl[srow][sseg] = vlb0;
        *(u16x8*)&Bl[srow + 64][sseg] = vlb1;
        __syncthreads();
        bf16x8 afh[4], afl[4], bfh[4], bfl[4];
#pragma unroll
        for (int fr = 0; fr < 4; ++fr) {
            afh[fr] = *(const bf16x8*)&Ah[rA + fr * 16][kb];
            afl[fr] = *(const bf16x8*)&Al[rA + fr * 16][kb];
        }
#pragma unroll
        for (int fc = 0; fc < 4; ++fc) {
            bfh[fc] = *(const bf16x8*)&Bh[rB + fc * 16][kb];
            bfl[fc] = *(const bf16x8*)&Bl[rB + fc * 16][kb];
        }
#pragma unroll
        for (int fr = 0; fr < 4; ++fr)
#pragma unroll
            for (int fc = 0; fc < 4; ++fc) {
                acc[fr][fc] = __builtin_amdgcn_mfma_f32_16x16x32_bf16(
                    afh[fr], bfh[fc], acc[fr][fc], 0, 0, 0);
                acc[fr][fc] = __builtin_amdgcn_mfma_f32_16x16x32_bf16(
                    afh[fr], bfl[fc], acc[fr][fc], 0, 0, 0);
                acc[fr][fc] = __builtin_amdgcn_mfma_f32_16x16x32_bf16(
                    afl[fr], bfh[fc], acc[fr][fc], 0, 0, 0);
            }
    }
    // epilogue: h store + fused att dots
    int colb = tn * 128 + wc * 64;
    int hd = colb >> 6;
    int rowg0 = tm * 128 + wr * 64 + ((l >> 4) << 2);
#pragma unroll
    for (int fr = 0; fr < 4; ++fr)
#pragma unroll
        for (int fc = 0; fc < 4; ++fc) {
            int col = colb + fc * 16 + (l & 15);
#pragma unroll
            for (int reg = 0; reg < 4; ++reg) {
                int row = rowg0 + fr * 16 + reg;
                hout[((size_t)row << 8) + col] = acc[fr][fc][reg];
            }
        }
    float asf[4], adf[4];
#pragma unroll
    for (int fc = 0; fc < 4; ++fc) {
        asf[fc] = att_s[hd * CC + fc * 16 + (l & 15)];
        adf[fc] = att_d[hd * CC + fc * 16 + (l & 15)];
    }
#pragma unroll
    for (int fr = 0; fr < 4; ++fr)
#pragma unroll
        for (int reg = 0; reg < 4; ++reg) {
            float s = acc[fr][0][reg] * asf[0] + acc[fr][1][reg] * asf[1] +
                      acc[fr][2][reg] * asf[2] + acc[fr][3][reg] * asf[3];
            float d = acc[fr][0][reg] * adf[0] + acc[fr][1][reg] * adf[1] +
                      acc[fr][2][reg] * adf[2] + acc[fr][3][reg] * adf[3];
#pragma unroll
            for (int o = 8; o; o >>= 1) {
                s += __shfl_xor(s, o);
                d += __shfl_xor(d, o);
            }
            if ((l & 15) == 0) {
                int row = rowg0 + fr * 16 + reg;
                as[row * HH + hd] = s;
                ad[row * HH + hd] = d;
            }
        }
}

// ---------------- FC head: relu(y@fc0_w + fc0_b) @ fc1_w + fc1_b ----------
__global__ __launch_bounds__(128) void k_fc(
    const float* __restrict__ y, const float* __restrict__ w0,
    const float* __restrict__ b0f, const float* __restrict__ w1,
    const float* __restrict__ b1f, float* __restrict__ out) {
    int t = threadIdx.x;
    int bn0 = blockIdx.x * 16;
    __shared__ float ys[16 * HC];
    for (int idx = t; idx < 16 * HC; idx += 128)
        ys[idx] = y[(size_t)bn0 * HC + idx];
    __syncthreads();
    float acc[16];
#pragma unroll
    for (int i = 0; i < 16; ++i) acc[i] = 0.f;
    for (int k = 0; k < HC; k += 4) {
        float wa = w0[k * NFC0 + t];
        float wb = w0[(k + 1) * NFC0 + t];
        float wc = w0[(k + 2) * NFC0 + t];
        float wd = w0[(k + 3) * NFC0 + t];
#pragma unroll
        for (int i = 0; i < 16; ++i) {
            float4 yv = *(const float4*)&ys[i * HC + k];
            acc[i] += yv.x * wa + yv.y * wb + yv.z * wc + yv.w * wd;
        }
    }
    float bb = b0f[t], w1v = w1[t];
    __shared__ float red[2][16];
    float part[16];
#pragma unroll
    for (int i = 0; i < 16; ++i) {
        float z = acc[i] + bb;
        z = z > 0.f ? z : 0.f;
        part[i] = z * w1v;
    }
#pragma unroll
    for (int i = 0; i < 16; ++i) {
        float v = part[i];
        for (int o = 32; o; o >>= 1) v += __shfl_down(v, o);
        if ((t & 63) == 0) red[t >> 6][i] = v;
    }
    __syncthreads();
    if (t < 16) out[bn0 + t] = red[0][t] + red[1][t] + b1f[0];
}

// ---------------- launch ----------------
extern "C" void kernel_launch(void* const* d_in, const int* in_sizes, int n_in,
                              void* d_out, int out_size, void* d_ws, size_t ws_size,
                              hipStream_t stream) {
    const float* x = (const float*)d_in[0];
    const int* ei0 = (const int*)d_in[2];
    const int* ei1 = (const int*)d_in[3];
    const float* W0 = (const float*)d_in[4];
    const float* atts0 = (const float*)d_in[5];
    const float* attd0 = (const float*)d_in[6];
    const float* b0 = (const float*)d_in[7];
    const float* W1 = (const float*)d_in[8];
    const float* atts1 = (const float*)d_in[9];
    const float* attd1 = (const float*)d_in[10];
    const float* b1 = (const float*)d_in[11];
    const float* fc0w = (const float*)d_in[12];
    const float* fc0b = (const float*)d_in[13];
    const float* fc1w = (const float*)d_in[14];
    const float* fc1b = (const float*)d_in[15];
    float* out = (float*)d_out;

    size_t BNHC = (size_t)BB * NN * HC;
    size_t BNH = (size_t)BB * NN * HH;
    float* fw = (float*)d_ws;
    float* h = fw;
    float* out0 = h + BNHC;
    float* y2 = out0 + BNHC;
    float* as0 = y2 + BNHC;
    float* ad0 = as0 + BNH;
    float* as1 = ad0 + BNH;
    float* ad1 = as1 + BNH;
    int* ip = (int*)(ad1 + BNH);
    int* off = ip; ip += 2 * (NN + 1);
    int* cnt = ip; ip += 2 * NN;
    int* csr = ip;

    // aliases: y_hi/y_lo live in y2's region (dead until aggregate1 writes y2);
    // W1^T hi/lo live in ad0's region (dead after aggregate0 reads it).
    u16* yhi = (u16*)y2;
    u16* ylo = yhi + BNHC;
    u16* wthi = (u16*)ad0;
    u16* wtlo = wthi + HC * HC;

    hipMemsetAsync(cnt, 0, 2 * NN * sizeof(int), stream);
    k_count2<<<128, 256, 0, stream>>>(ei0, ei1, cnt);
    k_scan2<<<2, NN, 0, stream>>>(cnt, off);
    k_scatter2<<<128, 256, 0, stream>>>(ei0, ei1, cnt, csr);

    // layer 0
    k_transform0<<<BB * NN, 256, 0, stream>>>(x, W0, atts0, attd0, h, as0, ad0);
    k_aggregate3<<<BB * NN / 4, 256, 0, stream>>>(h, as0, ad0, off, csr, b0,
                                                  nullptr, out0, yhi, ylo);
    // layer 1 (+ residual)
    k_prepW<<<HC, HC, 0, stream>>>(W1, wthi, wtlo);
    k_transform1_mfma<<<(BB * NN / 128) * 2, 256, 0, stream>>>(
        yhi, ylo, wthi, wtlo, atts1, attd1, h, as1, ad1);
    k_aggregate3<<<BB * NN / 4, 256, 0, stream>>>(h, as1, ad1, off + (NN + 1),
                                                  csr + EE, b1, out0, y2,
                                                  nullptr, nullptr);
    // FC head
    k_fc<<<BB * NN / 16, 128, 0, stream>>>(y2, fc0w, fc0b, fc1w, fc1b, out);
}

// Round 4
// 254.031 us; speedup vs baseline: 1.8953x; 1.2746x over previous
//
#include <hip/hip_runtime.h>

#define BB 32
#define NN 1024
#define EE 16384
#define HH 4
#define NEG 0.2f

// ---------------- float4 helpers ----------------
__device__ __forceinline__ float4 f4(float v) { return make_float4(v, v, v, v); }
__device__ __forceinline__ float4 f4max(float4 a, float4 b) {
    return make_float4(fmaxf(a.x, b.x), fmaxf(a.y, b.y), fmaxf(a.z, b.z), fmaxf(a.w, b.w));
}
__device__ __forceinline__ float4 f4add(float4 a, float4 b) {
    return make_float4(a.x + b.x, a.y + b.y, a.z + b.z, a.w + b.w);
}
__device__ __forceinline__ float4 f4sub(float4 a, float4 b) {
    return make_float4(a.x - b.x, a.y - b.y, a.z - b.z, a.w - b.w);
}
__device__ __forceinline__ float4 f4exp(float4 a) {
    return make_float4(__expf(a.x), __expf(a.y), __expf(a.z), __expf(a.w));
}
__device__ __forceinline__ float4 shflx4(float4 v, int o) {
    return make_float4(__shfl_xor(v.x, o), __shfl_xor(v.y, o),
                       __shfl_xor(v.z, o), __shfl_xor(v.w, o));
}
__device__ __forceinline__ float selh(float4 v, int h) {
    return h == 0 ? v.x : h == 1 ? v.y : h == 2 ? v.z : v.w;
}
__device__ __forceinline__ float4 leaky4(float4 z) {
    return make_float4(z.x > 0.f ? z.x : NEG * z.x, z.y > 0.f ? z.y : NEG * z.y,
                       z.z > 0.f ? z.z : NEG * z.z, z.w > 0.f ? z.w : NEG * z.w);
}

// ---------------- CSR build ----------------
__global__ void k_count2(const int* __restrict__ ei0, const int* __restrict__ ei1,
                         int* __restrict__ cnt) {
    int list = blockIdx.x >> 6;
    int e = ((blockIdx.x & 63) << 8) + threadIdx.x;
    const int* ei = list ? ei1 : ei0;
    atomicAdd(&cnt[(list << 10) + ei[EE + e]], 1);
}

__global__ void k_scan2(int* __restrict__ cnt, int* __restrict__ off) {
    __shared__ int s[NN];
    int list = blockIdx.x;
    int* c = cnt + (list << 10);
    int* o = off + list * (NN + 1);
    int t = threadIdx.x;
    int v0 = c[t];
    s[t] = v0;
    __syncthreads();
    for (int d = 1; d < NN; d <<= 1) {
        int v = (t >= d) ? s[t - d] : 0;
        __syncthreads();
        s[t] += v;
        __syncthreads();
    }
    int excl = s[t] - v0;
    o[t] = excl;
    c[t] = excl;
    if (t == NN - 1) o[NN] = s[NN - 1];
}

__global__ void k_scatter2(const int* __restrict__ ei0, const int* __restrict__ ei1,
                           int* __restrict__ cur, int* __restrict__ csr) {
    int list = blockIdx.x >> 6;
    int e = ((blockIdx.x & 63) << 8) + threadIdx.x;
    const int* ei = list ? ei1 : ei0;
    int sv = ei[e];
    int d = ei[EE + e];
    int p = atomicAdd(&cur[(list << 10) + d], 1);
    csr[(list << 14) + p] = sv;
}

// ---------- weight folding, stage A (1 block) ----------
// ws1[t][h] = sum_c W1[t, h*64+c]*att_s1[h,c]  (LDS only)
// Ms[i=h'*4+f][h] = sum_c' W0[f, h'*64+c']*ws1[h'*64+c'][h]
// cs[h] = sum_t b0[t]*ws1[t][h]
// ws0[f][h] = sum_c W0[f, h*64+c]*att_s0[h,c]
// bbw1[t] = sum_t' b0[t']*W1[t',t]
// U[i][t] = sum_c' W0[f, h'*64+c']*W1[h'*64+c', t]
__global__ __launch_bounds__(256) void k_prepA(
    const float* __restrict__ W0, const float* __restrict__ W1,
    const float* __restrict__ atts0, const float* __restrict__ attd0,
    const float* __restrict__ atts1, const float* __restrict__ attd1,
    const float* __restrict__ b0,
    float* __restrict__ ws0g, float* __restrict__ wd0g,
    float* __restrict__ Msg, float* __restrict__ Mdg,
    float* __restrict__ csg, float* __restrict__ cdg,
    float* __restrict__ bbw1, float* __restrict__ Ug) {
    __shared__ float ws1s[256 * 4], wd1s[256 * 4];
    int t = threadIdx.x;
    for (int h = 0; h < 4; ++h) {
        float s = 0.f, d = 0.f;
        for (int c = 0; c < 64; ++c) {
            float w = W1[t * 256 + h * 64 + c];
            s += w * atts1[h * 64 + c];
            d += w * attd1[h * 64 + c];
        }
        ws1s[t * 4 + h] = s;
        wd1s[t * 4 + h] = d;
    }
    __syncthreads();
    if (t < 64) {
        int i = t >> 2, h = t & 3;
        int hp = i >> 2, f = i & 3;
        float ms = 0.f, md = 0.f;
        for (int c = 0; c < 64; ++c) {
            float w = W0[f * 256 + hp * 64 + c];
            ms += w * ws1s[(hp * 64 + c) * 4 + h];
            md += w * wd1s[(hp * 64 + c) * 4 + h];
        }
        Msg[i * 4 + h] = ms;
        Mdg[i * 4 + h] = md;
    } else if (t < 72) {
        int h = t & 3, sel = (t - 64) >> 2;
        float a = 0.f;
        for (int tt = 0; tt < 256; ++tt)
            a += b0[tt] * (sel ? wd1s[tt * 4 + h] : ws1s[tt * 4 + h]);
        if (sel) cdg[h] = a; else csg[h] = a;
    } else if (t >= 96 && t < 128) {
        int e = t - 96, sel = e >> 4, i = e & 15;
        int f = i >> 2, h = i & 3;
        const float* att = sel ? attd0 : atts0;
        float a = 0.f;
        for (int c = 0; c < 64; ++c) a += W0[f * 256 + h * 64 + c] * att[h * 64 + c];
        (sel ? wd0g : ws0g)[f * 4 + h] = a;
    }
    {
        float a = 0.f;
        for (int tp = 0; tp < 256; ++tp) a += b0[tp] * W1[tp * 256 + t];
        bbw1[t] = a;
    }
    for (int j = 0; j < 16; ++j) {
        int e = t + (j << 8);
        int i = e >> 8, tt = e & 255;
        int hp = i >> 2, f = i & 3;
        float a = 0.f;
        for (int c = 0; c < 64; ++c)
            a += W0[f * 256 + hp * 64 + c] * W1[(hp * 64 + c) * 256 + tt];
        Ug[i * 256 + tt] = a;
    }
}

// ---------- weight folding, stage B ----------
// Wcat rows 0..63:  [h*16+j][u] = sum_c U[j][h*64+c]*fc0w[h*64+c, u]
// Wcat rows 64..79: [64+h*4+f][u] = sum_c W0[f, h*64+c]*fc0w[h*64+c, u]
// c2a[u] = sum_t (b1+b0)[t]*fc0w[t,u] + fc0b[u];  c2b[u] = sum_t bbw1[t]*fc0w[t,u]
__global__ __launch_bounds__(256) void k_prepB(
    const float* __restrict__ W0, const float* __restrict__ fc0w,
    const float* __restrict__ fc0b, const float* __restrict__ b0,
    const float* __restrict__ b1, const float* __restrict__ bbw1,
    const float* __restrict__ Ug, float* __restrict__ Wcat,
    float* __restrict__ c2a, float* __restrict__ c2b) {
    int gid = (blockIdx.x << 8) + threadIdx.x;
    if (gid < 8192) {
        int row = gid >> 7, u = gid & 127;
        int h = row >> 4, j = row & 15;
        float a = 0.f;
        for (int c = 0; c < 64; ++c)
            a += Ug[j * 256 + h * 64 + c] * fc0w[(h * 64 + c) * 128 + u];
        Wcat[row * 128 + u] = a;
    } else if (gid < 10240) {
        int row = gid >> 7, u = gid & 127;
        int j = row - 64;
        int h = j >> 2, f = j & 3;
        float a = 0.f;
        for (int c = 0; c < 64; ++c)
            a += W0[f * 256 + h * 64 + c] * fc0w[(h * 64 + c) * 128 + u];
        Wcat[row * 128 + u] = a;
    } else if (gid < 10368) {
        int u = gid - 10240;
        float a = fc0b[u];
        for (int tt = 0; tt < 256; ++tt) a += (b1[tt] + b0[tt]) * fc0w[tt * 128 + u];
        c2a[u] = a;
    } else if (gid < 10496) {
        int u = gid - 10368;
        float a = 0.f;
        for (int tt = 0; tt < 256; ++tt) a += bbw1[tt] * fc0w[tt * 128 + u];
        c2b[u] = a;
    }
}

// ---------- as0/ad0 = x . ws0/wd0 ----------
__global__ __launch_bounds__(256) void k_att0(
    const float* __restrict__ x, const float* __restrict__ ws0g,
    const float* __restrict__ wd0g, float* __restrict__ as0,
    float* __restrict__ ad0) {
    int bn = (blockIdx.x << 8) + threadIdx.x;
    float4 xv = *(const float4*)&x[bn << 2];
    float4 s, d;
    s.x = xv.x * ws0g[0] + xv.y * ws0g[4] + xv.z * ws0g[8] + xv.w * ws0g[12];
    s.y = xv.x * ws0g[1] + xv.y * ws0g[5] + xv.z * ws0g[9] + xv.w * ws0g[13];
    s.z = xv.x * ws0g[2] + xv.y * ws0g[6] + xv.z * ws0g[10] + xv.w * ws0g[14];
    s.w = xv.x * ws0g[3] + xv.y * ws0g[7] + xv.z * ws0g[11] + xv.w * ws0g[15];
    d.x = xv.x * wd0g[0] + xv.y * wd0g[4] + xv.z * wd0g[8] + xv.w * wd0g[12];
    d.y = xv.x * wd0g[1] + xv.y * wd0g[5] + xv.z * wd0g[9] + xv.w * wd0g[13];
    d.z = xv.x * wd0g[2] + xv.y * wd0g[6] + xv.z * wd0g[10] + xv.w * wd0g[14];
    d.w = xv.x * wd0g[3] + xv.y * wd0g[7] + xv.z * wd0g[11] + xv.w * wd0g[15];
    *(float4*)&as0[bn << 2] = s;
    *(float4*)&ad0[bn << 2] = d;
}

// ---------- layer-0 aggregate: xbar[n][h*4+f] = norm sum_e a0[e,h]*x[src,f]
//            + fused as1/ad1 = xbar.Ms + cs ----------
__global__ __launch_bounds__(256) void k_agg0(
    const float* __restrict__ x, const float* __restrict__ as0,
    const float* __restrict__ ad0, const int* __restrict__ off,
    const int* __restrict__ csr, const float* __restrict__ Msg,
    const float* __restrict__ Mdg, const float* __restrict__ csg,
    const float* __restrict__ cdg, float* __restrict__ xbar,
    float* __restrict__ as1, float* __restrict__ ad1) {
    int t = threadIdx.x;
    int wid = t >> 6, tw = t & 63;
    int bn = (blockIdx.x << 2) + wid;
    int b = bn >> 10, n = bn & (NN - 1);
    int beg = off[n], end = off[n + 1];
    float4 adv = *(const float4*)&ad0[bn << 2];
    float4 m4 = f4(-1e30f), den = f4(0.f);
    float pacc[16];
#pragma unroll
    for (int i = 0; i < 16; ++i) pacc[i] = 0.f;
    int nch = (end - beg + 63) >> 6;
    for (int c = 0; c < nch; ++c) {
        int base = beg + (c << 6);
        int m = end - base;
        if (m > 64) m = 64;
        float4 lv = f4(-1e30f), xs = f4(0.f);
        if (tw < m) {
            int s = csr[base + tw];
            float4 av = *(const float4*)&as0[((b << 10) + s) << 2];
            lv = leaky4(f4add(av, adv));
            xs = *(const float4*)&x[((b << 10) + s) << 2];
        }
        float4 cm = lv;
#pragma unroll
        for (int o = 32; o; o >>= 1) cm = f4max(cm, shflx4(cm, o));
        float4 nm = f4max(m4, cm);
        float4 r = f4exp(f4sub(m4, nm));
        m4 = nm;
        float4 ex = f4(0.f);
        if (tw < m) ex = f4exp(f4sub(lv, m4));
        float4 cd = ex;
#pragma unroll
        for (int o = 32; o; o >>= 1) cd = f4add(cd, shflx4(cd, o));
        den = f4add(make_float4(den.x * r.x, den.y * r.y, den.z * r.z, den.w * r.w), cd);
        float rr[4] = {r.x, r.y, r.z, r.w};
        float exa[4] = {ex.x, ex.y, ex.z, ex.w};
        float xsa[4] = {xs.x, xs.y, xs.z, xs.w};
        float p[16];
#pragma unroll
        for (int i = 0; i < 16; ++i) p[i] = exa[i >> 2] * xsa[i & 3];
#pragma unroll
        for (int o = 32; o; o >>= 1)
#pragma unroll
            for (int i = 0; i < 16; ++i) p[i] += __shfl_xor(p[i], o);
#pragma unroll
        for (int i = 0; i < 16; ++i) pacc[i] = pacc[i] * rr[i >> 2] + p[i];
    }
    float iva[4] = {1.f / (den.x + 1e-16f), 1.f / (den.y + 1e-16f),
                    1.f / (den.z + 1e-16f), 1.f / (den.w + 1e-16f)};
    float xbn[16];
#pragma unroll
    for (int i = 0; i < 16; ++i) xbn[i] = pacc[i] * iva[i >> 2];
    if (tw == 0) {
#pragma unroll
        for (int q = 0; q < 4; ++q) {
            float4 v = make_float4(xbn[q * 4], xbn[q * 4 + 1], xbn[q * 4 + 2],
                                   xbn[q * 4 + 3]);
            *(float4*)&xbar[(bn << 4) + (q << 2)] = v;
        }
    }
    if (tw < 8) {
        int h = tw & 3, sel = tw >> 2;
        const float* M = sel ? Mdg : Msg;
        float a = sel ? cdg[h] : csg[h];
#pragma unroll
        for (int i = 0; i < 16; ++i) a += xbn[i] * M[i * 4 + h];
        (sel ? ad1 : as1)[(bn << 2) + h] = a;
    }
}

// ---------- layer-1 aggregate: xb2[n][h*16+hf] = norm sum_e a1[e,h]*xbar[src,hf]
__global__ __launch_bounds__(256) void k_agg1(
    const float* __restrict__ xbar, const float* __restrict__ as1,
    const float* __restrict__ ad1, const int* __restrict__ off,
    const int* __restrict__ csr, float* __restrict__ xb2) {
    __shared__ int s_sh[4][64];
    __shared__ float e_sh[4][256];
    int t = threadIdx.x;
    int wid = t >> 6, tw = t & 63;
    int h = tw >> 4, hf = tw & 15;
    int bn = (blockIdx.x << 2) + wid;
    int b = bn >> 10, n = bn & (NN - 1);
    int beg = off[n], end = off[n + 1];
    float4 adv = *(const float4*)&ad1[bn << 2];
    float4 m4 = f4(-1e30f), den = f4(0.f);
    float acc = 0.f;
    const float* xbb = xbar + ((b << 10) << 4) + hf;
    int nch = (end - beg + 63) >> 6;
    for (int c = 0; c < nch; ++c) {
        int base = beg + (c << 6);
        int m = end - base;
        if (m > 64) m = 64;
        float4 lv = f4(-1e30f);
        if (tw < m) {
            int s = csr[base + tw];
            s_sh[wid][tw] = s;
            float4 av = *(const float4*)&as1[((b << 10) + s) << 2];
            lv = leaky4(f4add(av, adv));
        }
        float4 cm = lv;
#pragma unroll
        for (int o = 32; o; o >>= 1) cm = f4max(cm, shflx4(cm, o));
        float4 nm = f4max(m4, cm);
        float4 r = f4exp(f4sub(m4, nm));
        m4 = nm;
        float4 ex = f4(0.f);
        if (tw < m) ex = f4exp(f4sub(lv, m4));
        *(float4*)&e_sh[wid][tw << 2] = ex;
        float4 cd = ex;
#pragma unroll
        for (int o = 32; o; o >>= 1) cd = f4add(cd, shflx4(cd, o));
        den = f4add(make_float4(den.x * r.x, den.y * r.y, den.z * r.z, den.w * r.w), cd);
        acc *= selh(r, h);
        for (int j = 0; j < m; ++j) {
            int sj = s_sh[wid][j];
            float aj = e_sh[wid][(j << 2) + h];
            acc += aj * xbb[sj << 4];
        }
    }
    float dh = selh(den, h);
    acc *= 1.f / (dh + 1e-16f);
    xb2[(bn << 6) + tw] = acc;
}

// ---------- final: z = [xb2|xbar] @ Wcat + c2; out = relu(z).fc1w + fc1b ----------
#define AP 132
__global__ __launch_bounds__(256) void k_final(
    const float* __restrict__ xbar, const float* __restrict__ xb2,
    const float* __restrict__ Wcat, const float* __restrict__ c2a,
    const float* __restrict__ c2b, const float* __restrict__ fc1w,
    const float* __restrict__ fc1b, const int* __restrict__ off1,
    float* __restrict__ out) {
    __shared__ float Bs[80 * 128];
    __shared__ float As[80 * AP];
    __shared__ float c2as[128], c2bs[128], f1s[128];
    int t = threadIdx.x;
    int nb0 = blockIdx.x << 7;
    for (int i = t; i < 2560; i += 256) {
        float4 v = *(const float4*)&Wcat[i << 2];
        *(float4*)&Bs[i << 2] = v;
    }
    if (t < 128) {
        c2as[t] = c2a[t];
        c2bs[t] = c2b[t];
        f1s[t] = fc1w[t];
    }
#pragma unroll
    for (int i = 0; i < 8; ++i) {
        int q = t + (i << 8);
        int node = q >> 4, kq = q & 15;
        float4 v = *(const float4*)&xb2[((nb0 + node) << 6) + (kq << 2)];
        As[(kq * 4 + 0) * AP + node] = v.x;
        As[(kq * 4 + 1) * AP + node] = v.y;
        As[(kq * 4 + 2) * AP + node] = v.z;
        As[(kq * 4 + 3) * AP + node] = v.w;
    }
#pragma unroll
    for (int i = 0; i < 2; ++i) {
        int q = t + (i << 8);
        int node = q >> 2, kq = q & 3;
        float4 v = *(const float4*)&xbar[((nb0 + node) << 4) + (kq << 2)];
        As[(64 + kq * 4 + 0) * AP + node] = v.x;
        As[(64 + kq * 4 + 1) * AP + node] = v.y;
        As[(64 + kq * 4 + 2) * AP + node] = v.z;
        As[(64 + kq * 4 + 3) * AP + node] = v.w;
    }
    __syncthreads();
    int tx = t & 15, ty = t >> 4;
    int u0 = tx << 3, n0 = ty << 3;
    float za[8][8];
#pragma unroll
    for (int i = 0; i < 8; ++i)
#pragma unroll
        for (int j = 0; j < 8; ++j) za[i][j] = 0.f;
#pragma unroll 4
    for (int k = 0; k < 80; ++k) {
        float4 alo = *(const float4*)&As[k * AP + n0];
        float4 ahi = *(const float4*)&As[k * AP + n0 + 4];
        float4 blo = *(const float4*)&Bs[(k << 7) + u0];
        float4 bhi = *(const float4*)&Bs[(k << 7) + u0 + 4];
        float aa[8] = {alo.x, alo.y, alo.z, alo.w, ahi.x, ahi.y, ahi.z, ahi.w};
        float bb[8] = {blo.x, blo.y, blo.z, blo.w, bhi.x, bhi.y, bhi.z, bhi.w};
#pragma unroll
        for (int i = 0; i < 8; ++i)
#pragma unroll
            for (int j = 0; j < 8; ++j) za[i][j] += aa[i] * bb[j];
    }
    float fb = fc1b[0];
#pragma unroll
    for (int i = 0; i < 8; ++i) {
        int bnn = nb0 + n0 + i;
        int nl = bnn & (NN - 1);
        int deg = off1[nl + 1] - off1[nl];
        float part = 0.f;
#pragma unroll
        for (int j = 0; j < 8; ++j) {
            int u = u0 + j;
            float z = za[i][j] + c2as[u] + (deg > 0 ? c2bs[u] : 0.f);
            z = z > 0.f ? z : 0.f;
            part += z * f1s[u];
        }
#pragma unroll
        for (int o = 8; o; o >>= 1) part += __shfl_xor(part, o);
        if (tx == 0) out[bnn] = part + fb;
    }
}

// ---------------- launch ----------------
extern "C" void kernel_launch(void* const* d_in, const int* in_sizes, int n_in,
                              void* d_out, int out_size, void* d_ws, size_t ws_size,
                              hipStream_t stream) {
    const float* x = (const float*)d_in[0];
    const int* ei0 = (const int*)d_in[2];
    const int* ei1 = (const int*)d_in[3];
    const float* W0 = (const float*)d_in[4];
    const float* atts0 = (const float*)d_in[5];
    const float* attd0 = (const float*)d_in[6];
    const float* b0 = (const float*)d_in[7];
    const float* W1 = (const float*)d_in[8];
    const float* atts1 = (const float*)d_in[9];
    const float* attd1 = (const float*)d_in[10];
    const float* b1 = (const float*)d_in[11];
    const float* fc0w = (const float*)d_in[12];
    const float* fc0b = (const float*)d_in[13];
    const float* fc1w = (const float*)d_in[14];
    const float* fc1b = (const float*)d_in[15];
    float* out = (float*)d_out;

    float* fw = (float*)d_ws;
    float* xbar = fw;                 fw += (size_t)BB * NN * 16;
    float* xb2 = fw;                  fw += (size_t)BB * NN * 64;
    float* as0 = fw;                  fw += (size_t)BB * NN * 4;
    float* ad0 = fw;                  fw += (size_t)BB * NN * 4;
    float* as1 = fw;                  fw += (size_t)BB * NN * 4;
    float* ad1 = fw;                  fw += (size_t)BB * NN * 4;
    float* Ug = fw;                   fw += 4096;
    float* Wcat = fw;                 fw += 80 * 128;
    float* bbw1 = fw;                 fw += 256;
    float* c2a = fw;                  fw += 128;
    float* c2b = fw;                  fw += 128;
    float* ws0g = fw;                 fw += 16;
    float* wd0g = fw;                 fw += 16;
    float* Msg = fw;                  fw += 64;
    float* Mdg = fw;                  fw += 64;
    float* csg = fw;                  fw += 4;
    float* cdg = fw;                  fw += 4;
    int* ip = (int*)fw;
    int* off = ip;                    ip += 2 * (NN + 1);
    int* cnt = ip;                    ip += 2 * NN;
    int* csr = ip;

    hipMemsetAsync(cnt, 0, 2 * NN * sizeof(int), stream);
    k_count2<<<128, 256, 0, stream>>>(ei0, ei1, cnt);
    k_scan2<<<2, NN, 0, stream>>>(cnt, off);
    k_scatter2<<<128, 256, 0, stream>>>(ei0, ei1, cnt, csr);

    k_prepA<<<1, 256, 0, stream>>>(W0, W1, atts0, attd0, atts1, attd1, b0,
                                   ws0g, wd0g, Msg, Mdg, csg, cdg, bbw1, Ug);
    k_prepB<<<41, 256, 0, stream>>>(W0, fc0w, fc0b, b0, b1, bbw1, Ug, Wcat,
                                    c2a, c2b);
    k_att0<<<BB * NN / 256, 256, 0, stream>>>(x, ws0g, wd0g, as0, ad0);
    k_agg0<<<BB * NN / 4, 256, 0, stream>>>(x, as0, ad0, off, csr, Msg, Mdg,
                                            csg, cdg, xbar, as1, ad1);
    k_agg1<<<BB * NN / 4, 256, 0, stream>>>(xbar, as1, ad1, off + (NN + 1),
                                            csr + EE, xb2);
    k_final<<<BB * NN / 128, 256, 0, stream>>>(xbar, xb2, Wcat, c2a, c2b, fc1w,
                                               fc1b, off + (NN + 1), out);
}

// Round 6
// 178.290 us; speedup vs baseline: 2.7005x; 1.4248x over previous
//
#include <hip/hip_runtime.h>

#define BB 32
#define NN 1024
#define EE 16384
#define HH 4
#define NEG 0.2f

// ---------------- float4 helpers ----------------
__device__ __forceinline__ float4 f4(float v) { return make_float4(v, v, v, v); }
__device__ __forceinline__ float4 f4max(float4 a, float4 b) {
    return make_float4(fmaxf(a.x, b.x), fmaxf(a.y, b.y), fmaxf(a.z, b.z), fmaxf(a.w, b.w));
}
__device__ __forceinline__ float4 f4add(float4 a, float4 b) {
    return make_float4(a.x + b.x, a.y + b.y, a.z + b.z, a.w + b.w);
}
__device__ __forceinline__ float4 f4sub(float4 a, float4 b) {
    return make_float4(a.x - b.x, a.y - b.y, a.z - b.z, a.w - b.w);
}
__device__ __forceinline__ float4 f4mul(float4 a, float4 b) {
    return make_float4(a.x * b.x, a.y * b.y, a.z * b.z, a.w * b.w);
}
__device__ __forceinline__ float4 f4exp(float4 a) {
    return make_float4(__expf(a.x), __expf(a.y), __expf(a.z), __expf(a.w));
}
__device__ __forceinline__ float4 shflx4(float4 v, int o) {
    return make_float4(__shfl_xor(v.x, o), __shfl_xor(v.y, o),
                       __shfl_xor(v.z, o), __shfl_xor(v.w, o));
}
__device__ __forceinline__ float4 leaky4(float4 z) {
    return make_float4(z.x > 0.f ? z.x : NEG * z.x, z.y > 0.f ? z.y : NEG * z.y,
                       z.z > 0.f ? z.z : NEG * z.z, z.w > 0.f ? z.w : NEG * z.w);
}

// ======== L2: edge count (blocks 0..127) + weight-fold stage 1 (128..152) ===
// prep1 outputs: Ug[16][256], ws1g/wd1g[256*4] ([t][h]), ws0g/wd0g[16] ([f][h])
__global__ __launch_bounds__(256) void k_count_prep1(
    const int* __restrict__ ei0, const int* __restrict__ ei1,
    int* __restrict__ cnt, const float* __restrict__ W0,
    const float* __restrict__ W1, const float* __restrict__ atts0,
    const float* __restrict__ attd0, const float* __restrict__ atts1,
    const float* __restrict__ attd1, float* __restrict__ ws1g,
    float* __restrict__ wd1g, float* __restrict__ ws0g,
    float* __restrict__ wd0g, float* __restrict__ Ug) {
    int blk = blockIdx.x, t = threadIdx.x;
    if (blk < 128) {
        int list = blk >> 6;
        int e = ((blk & 63) << 8) + t;
        const int* ei = list ? ei1 : ei0;
        atomicAdd(&cnt[(list << 10) + ei[EE + e]], 1);
        return;
    }
    int gid = ((blk - 128) << 8) + t;
    if (gid < 4096) {
        // Ug[i][tt] = sum_c W0[f, hp*64+c] * W1[hp*64+c, tt], i = hp*4+f
        int i = gid >> 8, tt = gid & 255;
        int hp = i >> 2, f = i & 3;
        float a = 0.f;
        for (int c = 0; c < 64; ++c)
            a += W0[f * 256 + hp * 64 + c] * W1[(hp * 64 + c) * 256 + tt];
        Ug[i * 256 + tt] = a;
    } else if (gid < 5120) {
        int q = gid - 4096;
        int tt = q >> 2, h = q & 3;
        float a = 0.f;
        for (int c = 0; c < 64; ++c)
            a += W1[tt * 256 + h * 64 + c] * atts1[h * 64 + c];
        ws1g[q] = a;
    } else if (gid < 6144) {
        int q = gid - 5120;
        int tt = q >> 2, h = q & 3;
        float a = 0.f;
        for (int c = 0; c < 64; ++c)
            a += W1[tt * 256 + h * 64 + c] * attd1[h * 64 + c];
        wd1g[q] = a;
    } else if (gid < 6176) {
        int q = gid - 6144;
        int sel = q >> 4, i = q & 15;
        int f = i >> 2, h = i & 3;
        const float* att = sel ? attd0 : atts0;
        float a = 0.f;
        for (int c = 0; c < 64; ++c)
            a += W0[f * 256 + h * 64 + c] * att[h * 64 + c];
        (sel ? wd0g : ws0g)[i] = a;
    }
}

// ======== L3: exclusive scan per list ========
__global__ void k_scan2(int* __restrict__ cnt, int* __restrict__ off) {
    __shared__ int s[NN];
    int list = blockIdx.x;
    int* c = cnt + (list << 10);
    int* o = off + list * (NN + 1);
    int t = threadIdx.x;
    int v0 = c[t];
    s[t] = v0;
    __syncthreads();
    for (int d = 1; d < NN; d <<= 1) {
        int v = (t >= d) ? s[t - d] : 0;
        __syncthreads();
        s[t] += v;
        __syncthreads();
    }
    int excl = s[t] - v0;
    o[t] = excl;
    c[t] = excl;
    if (t == NN - 1) o[NN] = s[NN - 1];
}

// ======== L4: scatter (0..127) + prep2 (128..129) + att0 (130..257) ========
// prep2: Ms/Md[16][4], cs/cd[4], bbw1[256]
__global__ __launch_bounds__(256) void k_scat_prep2_att0(
    const int* __restrict__ ei0, const int* __restrict__ ei1,
    int* __restrict__ cur, int* __restrict__ csr,
    const float* __restrict__ W0, const float* __restrict__ W1,
    const float* __restrict__ b0, const float* __restrict__ ws1g,
    const float* __restrict__ wd1g, float* __restrict__ Msg,
    float* __restrict__ Mdg, float* __restrict__ csg, float* __restrict__ cdg,
    float* __restrict__ bbw1, const float* __restrict__ x,
    const float* __restrict__ ws0g, const float* __restrict__ wd0g,
    float* __restrict__ as0, float* __restrict__ ad0) {
    int blk = blockIdx.x, t = threadIdx.x;
    if (blk < 128) {
        int list = blk >> 6;
        int e = ((blk & 63) << 8) + t;
        const int* ei = list ? ei1 : ei0;
        int sv = ei[e];
        int d = ei[EE + e];
        int p = atomicAdd(&cur[(list << 10) + d], 1);
        csr[(list << 14) + p] = sv;
        return;
    }
    if (blk < 130) {
        int gid = ((blk - 128) << 8) + t;   // 0..511
        if (gid < 64) {
            int i = gid >> 2, h = gid & 3;
            int hp = i >> 2, f = i & 3;
            float a = 0.f;
            for (int c = 0; c < 64; ++c)
                a += W0[f * 256 + hp * 64 + c] * ws1g[(hp * 64 + c) * 4 + h];
            Msg[gid] = a;
        } else if (gid < 128) {
            int q = gid - 64;
            int i = q >> 2, h = q & 3;
            int hp = i >> 2, f = i & 3;
            float a = 0.f;
            for (int c = 0; c < 64; ++c)
                a += W0[f * 256 + hp * 64 + c] * wd1g[(hp * 64 + c) * 4 + h];
            Mdg[q] = a;
        } else if (gid < 132) {
            int h = gid - 128;
            float a = 0.f;
            for (int tt = 0; tt < 256; ++tt) a += b0[tt] * ws1g[tt * 4 + h];
            csg[h] = a;
        } else if (gid < 136) {
            int h = gid - 132;
            float a = 0.f;
            for (int tt = 0; tt < 256; ++tt) a += b0[tt] * wd1g[tt * 4 + h];
            cdg[h] = a;
        } else if (gid >= 256) {
            int tt = gid - 256;
            float a = 0.f;
            for (int tp = 0; tp < 256; ++tp) a += b0[tp] * W1[tp * 256 + tt];
            bbw1[tt] = a;
        }
        return;
    }
    // att0: as0/ad0 = x . ws0/wd0
    int bn = ((blk - 130) << 8) + t;
    float4 xv = *(const float4*)&x[bn << 2];
    float4 s, d;
    s.x = xv.x * ws0g[0] + xv.y * ws0g[4] + xv.z * ws0g[8] + xv.w * ws0g[12];
    s.y = xv.x * ws0g[1] + xv.y * ws0g[5] + xv.z * ws0g[9] + xv.w * ws0g[13];
    s.z = xv.x * ws0g[2] + xv.y * ws0g[6] + xv.z * ws0g[10] + xv.w * ws0g[14];
    s.w = xv.x * ws0g[3] + xv.y * ws0g[7] + xv.z * ws0g[11] + xv.w * ws0g[15];
    d.x = xv.x * wd0g[0] + xv.y * wd0g[4] + xv.z * wd0g[8] + xv.w * wd0g[12];
    d.y = xv.x * wd0g[1] + xv.y * wd0g[5] + xv.z * wd0g[9] + xv.w * wd0g[13];
    d.z = xv.x * wd0g[2] + xv.y * wd0g[6] + xv.z * wd0g[10] + xv.w * wd0g[14];
    d.w = xv.x * wd0g[3] + xv.y * wd0g[7] + xv.z * wd0g[11] + xv.w * wd0g[15];
    *(float4*)&as0[bn << 2] = s;
    *(float4*)&ad0[bn << 2] = d;
}

// ======== L5: agg0 (blocks 0..2047, 16-lane group per node) + prepB =========
__global__ __launch_bounds__(256) void k_agg0_prepB(
    const float* __restrict__ x, const float* __restrict__ as0,
    const float* __restrict__ ad0, const int* __restrict__ off,
    const int* __restrict__ csr, const float* __restrict__ Msg,
    const float* __restrict__ Mdg, const float* __restrict__ csg,
    const float* __restrict__ cdg, float* __restrict__ xbar,
    float* __restrict__ as1, float* __restrict__ ad1,
    const float* __restrict__ W0, const float* __restrict__ fc0w,
    const float* __restrict__ fc0b, const float* __restrict__ b0,
    const float* __restrict__ b1, const float* __restrict__ bbw1,
    const float* __restrict__ Ug, float* __restrict__ Wcat,
    float* __restrict__ c2a, float* __restrict__ c2b) {
    int blk = blockIdx.x, t = threadIdx.x;
    if (blk >= 2048) {
        // prepB
        int gid = ((blk - 2048) << 8) + t;
        if (gid < 8192) {
            int row = gid >> 7, u = gid & 127;
            int h = row >> 4, j = row & 15;
            float a = 0.f;
            for (int c = 0; c < 64; ++c)
                a += Ug[j * 256 + h * 64 + c] * fc0w[(h * 64 + c) * 128 + u];
            Wcat[row * 128 + u] = a;
        } else if (gid < 10240) {
            int row = gid >> 7, u = gid & 127;
            int j = row - 64;
            int h = j >> 2, f = j & 3;
            float a = 0.f;
            for (int c = 0; c < 64; ++c)
                a += W0[f * 256 + h * 64 + c] * fc0w[(h * 64 + c) * 128 + u];
            Wcat[row * 128 + u] = a;
        } else if (gid < 10368) {
            int u = gid - 10240;
            float a = fc0b[u];
            for (int tt = 0; tt < 256; ++tt)
                a += (b1[tt] + b0[tt]) * fc0w[tt * 128 + u];
            c2a[u] = a;
        } else if (gid < 10496) {
            int u = gid - 10368;
            float a = 0.f;
            for (int tt = 0; tt < 256; ++tt) a += bbw1[tt] * fc0w[tt * 128 + u];
            c2b[u] = a;
        }
        return;
    }
    // agg0: 16 lanes per node, per-lane deferred online softmax
    int g = t >> 4, l = t & 15;
    int bn = (blk << 4) + g;
    int b = bn >> 10, n = bn & (NN - 1);
    int beg = off[n], end = off[n + 1];
    float4 adv = *(const float4*)&ad0[bn << 2];
    float4 m4 = f4(-1e30f), den = f4(0.f);
    float pacc[16];
#pragma unroll
    for (int i = 0; i < 16; ++i) pacc[i] = 0.f;
    for (int base = beg + l; base < end; base += 16) {
        int s = csr[base];
        float4 av = *(const float4*)&as0[((b << 10) + s) << 2];
        float4 xs = *(const float4*)&x[((b << 10) + s) << 2];
        float4 lv = leaky4(f4add(av, adv));
        float4 nm = f4max(m4, lv);
        float4 r = f4exp(f4sub(m4, nm));
        float4 ex = f4exp(f4sub(lv, nm));
        m4 = nm;
        den = f4add(f4mul(den, r), ex);
        float rr[4] = {r.x, r.y, r.z, r.w};
        float exa[4] = {ex.x, ex.y, ex.z, ex.w};
        float xsa[4] = {xs.x, xs.y, xs.z, xs.w};
#pragma unroll
        for (int i = 0; i < 16; ++i)
            pacc[i] = pacc[i] * rr[i >> 2] + exa[i >> 2] * xsa[i & 3];
    }
    // allreduce within 16-lane group (masks 1,2,4,8)
    float4 ml = m4;
#pragma unroll
    for (int o = 8; o; o >>= 1) m4 = f4max(m4, shflx4(m4, o));
    float4 sc = f4exp(f4sub(ml, m4));
    den = f4mul(den, sc);
    float sca[4] = {sc.x, sc.y, sc.z, sc.w};
#pragma unroll
    for (int i = 0; i < 16; ++i) pacc[i] *= sca[i >> 2];
#pragma unroll
    for (int o = 8; o; o >>= 1) {
        den = f4add(den, shflx4(den, o));
#pragma unroll
        for (int i = 0; i < 16; ++i) pacc[i] += __shfl_xor(pacc[i], o);
    }
    float iva[4] = {1.f / (den.x + 1e-16f), 1.f / (den.y + 1e-16f),
                    1.f / (den.z + 1e-16f), 1.f / (den.w + 1e-16f)};
    float xbn[16];
#pragma unroll
    for (int i = 0; i < 16; ++i) xbn[i] = pacc[i] * iva[i >> 2];
    if (l == 0) {
#pragma unroll
        for (int q = 0; q < 4; ++q) {
            float4 v = make_float4(xbn[q * 4], xbn[q * 4 + 1], xbn[q * 4 + 2],
                                   xbn[q * 4 + 3]);
            *(float4*)&xbar[(bn << 4) + (q << 2)] = v;
        }
    }
    if (l < 8) {
        int h = l & 3, sel = l >> 2;
        const float* M = sel ? Mdg : Msg;
        float a = sel ? cdg[h] : csg[h];
#pragma unroll
        for (int i = 0; i < 16; ++i) a += xbn[i] * M[i * 4 + h];
        (sel ? ad1 : as1)[(bn << 2) + h] = a;
    }
}

// ======== L6: agg1 — wave per node; lane = (h = tw>>4, slot = tw&15) =======
__global__ __launch_bounds__(256) void k_agg1(
    const float* __restrict__ xbar, const float* __restrict__ as1,
    const float* __restrict__ ad1, const int* __restrict__ off,
    const int* __restrict__ csr, float* __restrict__ xb2) {
    int t = threadIdx.x;
    int wid = t >> 6, tw = t & 63;
    int h = tw >> 4, slot = tw & 15;
    int bn = (blockIdx.x << 2) + wid;
    int b = bn >> 10, n = bn & (NN - 1);
    int beg = off[n], end = off[n + 1];
    float adh = ad1[(bn << 2) + h];
    float ml = -1e30f, den = 0.f;
    float pacc[16];
#pragma unroll
    for (int i = 0; i < 16; ++i) pacc[i] = 0.f;
    const float* xbb = xbar + ((size_t)b << 14);
    for (int base = beg + slot; base < end; base += 16) {
        int s = csr[base];
        float av = as1[(((b << 10) + s) << 2) + h];
        float z = av + adh;
        float lv = z > 0.f ? z : NEG * z;
        float nm = fmaxf(ml, lv);
        float r = __expf(ml - nm);
        float ex = __expf(lv - nm);
        ml = nm;
        den = den * r + ex;
        const float* xp = xbb + (s << 4);
        float4 x0 = *(const float4*)(xp);
        float4 x1 = *(const float4*)(xp + 4);
        float4 x2 = *(const float4*)(xp + 8);
        float4 x3 = *(const float4*)(xp + 12);
        float xsa[16] = {x0.x, x0.y, x0.z, x0.w, x1.x, x1.y, x1.z, x1.w,
                         x2.x, x2.y, x2.z, x2.w, x3.x, x3.y, x3.z, x3.w};
#pragma unroll
        for (int i = 0; i < 16; ++i) pacc[i] = pacc[i] * r + ex * xsa[i];
    }
    // reduce across 16 slots (masks 1,2,4,8 — within 16-lane group, same h)
    float M = ml;
#pragma unroll
    for (int o = 8; o; o >>= 1) M = fmaxf(M, __shfl_xor(M, o));
    float sc = __expf(ml - M);
    den *= sc;
#pragma unroll
    for (int i = 0; i < 16; ++i) pacc[i] *= sc;
#pragma unroll
    for (int o = 8; o; o >>= 1) {
        den += __shfl_xor(den, o);
#pragma unroll
        for (int i = 0; i < 16; ++i) pacc[i] += __shfl_xor(pacc[i], o);
    }
    float inv = 1.f / (den + 1e-16f);
    if (slot == 0) {
#pragma unroll
        for (int q = 0; q < 4; ++q) {
            float4 v = make_float4(pacc[q * 4] * inv, pacc[q * 4 + 1] * inv,
                                   pacc[q * 4 + 2] * inv, pacc[q * 4 + 3] * inv);
            *(float4*)&xb2[(bn << 6) + (h << 4) + (q << 2)] = v;
        }
    }
}

// ======== L7: final GEMM + ReLU + 128-dot ========
#define AP 132
__global__ __launch_bounds__(256) void k_final(
    const float* __restrict__ xbar, const float* __restrict__ xb2,
    const float* __restrict__ Wcat, const float* __restrict__ c2a,
    const float* __restrict__ c2b, const float* __restrict__ fc1w,
    const float* __restrict__ fc1b, const int* __restrict__ off1,
    float* __restrict__ out) {
    __shared__ float Bs[80 * 128];
    __shared__ float As[80 * AP];
    __shared__ float c2as[128], c2bs[128], f1s[128];
    int t = threadIdx.x;
    int nb0 = blockIdx.x << 7;
    for (int i = t; i < 2560; i += 256) {
        float4 v = *(const float4*)&Wcat[i << 2];
        *(float4*)&Bs[i << 2] = v;
    }
    if (t < 128) {
        c2as[t] = c2a[t];
        c2bs[t] = c2b[t];
        f1s[t] = fc1w[t];
    }
#pragma unroll
    for (int i = 0; i < 8; ++i) {
        int q = t + (i << 8);
        int node = q >> 4, kq = q & 15;
        float4 v = *(const float4*)&xb2[((nb0 + node) << 6) + (kq << 2)];
        As[(kq * 4 + 0) * AP + node] = v.x;
        As[(kq * 4 + 1) * AP + node] = v.y;
        As[(kq * 4 + 2) * AP + node] = v.z;
        As[(kq * 4 + 3) * AP + node] = v.w;
    }
#pragma unroll
    for (int i = 0; i < 2; ++i) {
        int q = t + (i << 8);
        int node = q >> 2, kq = q & 3;
        float4 v = *(const float4*)&xbar[((nb0 + node) << 4) + (kq << 2)];
        As[(64 + kq * 4 + 0) * AP + node] = v.x;
        As[(64 + kq * 4 + 1) * AP + node] = v.y;
        As[(64 + kq * 4 + 2) * AP + node] = v.z;
        As[(64 + kq * 4 + 3) * AP + node] = v.w;
    }
    __syncthreads();
    int tx = t & 15, ty = t >> 4;
    int u0 = tx << 3, n0 = ty << 3;
    float za[8][8];
#pragma unroll
    for (int i = 0; i < 8; ++i)
#pragma unroll
        for (int j = 0; j < 8; ++j) za[i][j] = 0.f;
#pragma unroll 4
    for (int k = 0; k < 80; ++k) {
        float4 alo = *(const float4*)&As[k * AP + n0];
        float4 ahi = *(const float4*)&As[k * AP + n0 + 4];
        float4 blo = *(const float4*)&Bs[(k << 7) + u0];
        float4 bhi = *(const float4*)&Bs[(k << 7) + u0 + 4];
        float aa[8] = {alo.x, alo.y, alo.z, alo.w, ahi.x, ahi.y, ahi.z, ahi.w};
        float bb[8] = {blo.x, blo.y, blo.z, blo.w, bhi.x, bhi.y, bhi.z, bhi.w};
#pragma unroll
        for (int i = 0; i < 8; ++i)
#pragma unroll
            for (int j = 0; j < 8; ++j) za[i][j] += aa[i] * bb[j];
    }
    float fb = fc1b[0];
#pragma unroll
    for (int i = 0; i < 8; ++i) {
        int bnn = nb0 + n0 + i;
        int nl = bnn & (NN - 1);
        int deg = off1[nl + 1] - off1[nl];
        float part = 0.f;
#pragma unroll
        for (int j = 0; j < 8; ++j) {
            int u = u0 + j;
            float z = za[i][j] + c2as[u] + (deg > 0 ? c2bs[u] : 0.f);
            z = z > 0.f ? z : 0.f;
            part += z * f1s[u];
        }
#pragma unroll
        for (int o = 8; o; o >>= 1) part += __shfl_xor(part, o);
        if (tx == 0) out[bnn] = part + fb;
    }
}

// ---------------- launch ----------------
extern "C" void kernel_launch(void* const* d_in, const int* in_sizes, int n_in,
                              void* d_out, int out_size, void* d_ws, size_t ws_size,
                              hipStream_t stream) {
    const float* x = (const float*)d_in[0];
    const int* ei0 = (const int*)d_in[2];
    const int* ei1 = (const int*)d_in[3];
    const float* W0 = (const float*)d_in[4];
    const float* atts0 = (const float*)d_in[5];
    const float* attd0 = (const float*)d_in[6];
    const float* b0 = (const float*)d_in[7];
    const float* W1 = (const float*)d_in[8];
    const float* atts1 = (const float*)d_in[9];
    const float* attd1 = (const float*)d_in[10];
    const float* b1 = (const float*)d_in[11];
    const float* fc0w = (const float*)d_in[12];
    const float* fc0b = (const float*)d_in[13];
    const float* fc1w = (const float*)d_in[14];
    const float* fc1b = (const float*)d_in[15];
    float* out = (float*)d_out;

    float* fw = (float*)d_ws;
    float* xbar = fw;                 fw += (size_t)BB * NN * 16;
    float* xb2 = fw;                  fw += (size_t)BB * NN * 64;
    float* as0 = fw;                  fw += (size_t)BB * NN * 4;
    float* ad0 = fw;                  fw += (size_t)BB * NN * 4;
    float* as1 = fw;                  fw += (size_t)BB * NN * 4;
    float* ad1 = fw;                  fw += (size_t)BB * NN * 4;
    float* Ug = fw;                   fw += 4096;
    float* Wcat = fw;                 fw += 80 * 128;
    float* bbw1 = fw;                 fw += 256;
    float* c2a = fw;                  fw += 128;
    float* c2b = fw;                  fw += 128;
    float* ws0g = fw;                 fw += 16;
    float* wd0g = fw;                 fw += 16;
    float* Msg = fw;                  fw += 64;
    float* Mdg = fw;                  fw += 64;
    float* csg = fw;                  fw += 4;
    float* cdg = fw;                  fw += 4;
    float* ws1g = fw;                 fw += 1024;
    float* wd1g = fw;                 fw += 1024;
    int* ip = (int*)fw;
    int* off = ip;                    ip += 2 * (NN + 1);
    int* cnt = ip;                    ip += 2 * NN;
    int* csr = ip;

    hipMemsetAsync(cnt, 0, 2 * NN * sizeof(int), stream);
    k_count_prep1<<<153, 256, 0, stream>>>(ei0, ei1, cnt, W0, W1, atts0, attd0,
                                           atts1, attd1, ws1g, wd1g, ws0g,
                                           wd0g, Ug);
    k_scan2<<<2, NN, 0, stream>>>(cnt, off);
    k_scat_prep2_att0<<<258, 256, 0, stream>>>(
        ei0, ei1, cnt, csr, W0, W1, b0, ws1g, wd1g, Msg, Mdg, csg, cdg, bbw1,
        x, ws0g, wd0g, as0, ad0);
    k_agg0_prepB<<<2089, 256, 0, stream>>>(
        x, as0, ad0, off, csr, Msg, Mdg, csg, cdg, xbar, as1, ad1, W0, fc0w,
        fc0b, b0, b1, bbw1, Ug, Wcat, c2a, c2b);
    k_agg1<<<BB * NN / 4, 256, 0, stream>>>(xbar, as1, ad1, off + (NN + 1),
                                            csr + EE, xb2);
    k_final<<<BB * NN / 128, 256, 0, stream>>>(xbar, xb2, Wcat, c2a, c2b, fc1w,
                                               fc1b, off + (NN + 1), out);
}